// Round 1
// baseline (4062.465 us; speedup 1.0000x reference)
//
#include <hip/hip_runtime.h>
#include <math.h>

// Problem dims (fixed by setup_inputs)
#define BN 8
#define C1 256    // conv1 in/out channels, conv2 in channels
#define C2 128    // conv2 out channels
#define WD 512
#define H1 64
#define H2 128

#define TS 32     // spatial output tile
#define OCB 16    // output channels per block
#define ISTR 36   // LDS patch stride (floats), keeps rows 16B-aligned
#define SSTR 19   // LDS src patch stride for conv2 staging

__device__ __forceinline__ int clampi(int v, int lo, int hi) {
    return v < lo ? lo : (v > hi ? hi : v);
}

// ---------------- affine: styles1, styles2, noise1, noise2 ----------------
__global__ void affine_kernel(const float* __restrict__ w, const float* __restrict__ n,
                              const float* __restrict__ A1w, const float* __restrict__ A1b,
                              const float* __restrict__ B1w, const float* __restrict__ B1b,
                              const float* __restrict__ A2w, const float* __restrict__ A2b,
                              const float* __restrict__ B2w, const float* __restrict__ B2b,
                              float* __restrict__ s1, float* __restrict__ s2,
                              float* __restrict__ n1, float* __restrict__ n2) {
    int idx = blockIdx.x * blockDim.x + threadIdx.x;
    if (idx >= BN * 896) return;
    int b = idx / 896;
    int j = idx % 896;
    const float* vec; const float* M; const float* bias; float* out; int o;
    if (j < 256)      { o = j;       vec = w + b * WD; M = A1w; bias = A1b; out = s1 + b * 256; }
    else if (j < 512) { o = j - 256; vec = w + b * WD; M = A2w; bias = A2b; out = s2 + b * 256; }
    else if (j < 768) { o = j - 512; vec = n + b * WD; M = B1w; bias = B1b; out = n1 + b * 256; }
    else              { o = j - 768; vec = n + b * WD; M = B2w; bias = B2b; out = n2 + b * 128; }
    const float* row = M + (size_t)o * WD;
    float acc = 0.f;
    for (int k = 0; k < WD; k += 4) {
        acc += vec[k] * row[k] + vec[k+1] * row[k+1]
             + vec[k+2] * row[k+2] + vec[k+3] * row[k+3];
    }
    out[o] = acc + bias[o];
}

// ---------------- demod: d[b][o] = rsqrt(sum_i s^2 * sum_k w^2 + eps) ----------------
__global__ void demod_kernel(const float* __restrict__ cw1, const float* __restrict__ cw2,
                             const float* __restrict__ s1, const float* __restrict__ s2,
                             float* __restrict__ d1, float* __restrict__ d2) {
    int idx = blockIdx.x * blockDim.x + threadIdx.x;
    if (idx >= BN * 384) return;
    int b = idx / 384;
    int j = idx % 384;
    const float* wbase; const float* s; float* dout; int o;
    if (j < 256) { o = j;       wbase = cw1; s = s1 + b * 256; dout = d1 + b * 256; }
    else         { o = j - 256; wbase = cw2; s = s2 + b * 256; dout = d2 + b * 128; }
    const float* wr = wbase + (size_t)o * C1 * 9;
    float acc = 0.f;
    for (int i = 0; i < C1; i++) {
        float sv = s[i]; sv *= sv;
        const float* wk = wr + i * 9;
        float t = 0.f;
        #pragma unroll
        for (int k = 0; k < 9; k++) t += wk[k] * wk[k];
        acc += t * sv;
    }
    dout[o] = rsqrtf(acc + 1e-5f);
}

// ---------------- conv1: modulated 3x3, 256->256 @ 64x64, + noise + leaky ----------------
__global__ __launch_bounds__(256)
void conv1_kernel(const float* __restrict__ x, const float* __restrict__ cw,
                  const float* __restrict__ s1, const float* __restrict__ d1,
                  const float* __restrict__ n1, float* __restrict__ y1) {
    __shared__ __align__(16) float patch[34 * ISTR];
    int b    = blockIdx.z;
    int ocg  = blockIdx.y;              // 0..15
    int tile = blockIdx.x;              // 0..3
    int y0 = (tile >> 1) * TS;
    int x0 = (tile & 1) * TS;
    int tid = threadIdx.x;
    int ty  = tid >> 3;                 // 0..31
    int tx4 = (tid & 7) << 2;           // 0,4,...,28

    float acc[OCB][4];
    #pragma unroll
    for (int o = 0; o < OCB; o++)
        #pragma unroll
        for (int j = 0; j < 4; j++) acc[o][j] = 0.f;

    const float* sb = s1 + b * 256;
    for (int ic = 0; ic < C1; ic++) {
        __syncthreads();
        float sv = sb[ic];
        const float* xp = x + (((size_t)b * C1 + ic) << 12);
        for (int e = tid; e < 34 * 34; e += 256) {
            int r = e / 34, c = e % 34;
            int gy = y0 - 1 + r, gx = x0 - 1 + c;
            float v = 0.f;
            if (gy >= 0 && gy < 64 && gx >= 0 && gx < 64)
                v = xp[(gy << 6) + gx] * sv;
            patch[r * ISTR + c] = v;
        }
        __syncthreads();
        float a[3][6];
        #pragma unroll
        for (int kh = 0; kh < 3; kh++) {
            const float* p = &patch[(ty + kh) * ISTR + tx4];
            #pragma unroll
            for (int c = 0; c < 6; c++) a[kh][c] = p[c];
        }
        const float* wp = cw + ((size_t)(ocg * OCB) * C1 + ic) * 9;
        #pragma unroll
        for (int o = 0; o < OCB; o++) {
            const float* wo = wp + (size_t)o * C1 * 9;   // wave-uniform -> s_load
            float w0 = wo[0], w1 = wo[1], w2 = wo[2], w3 = wo[3], w4 = wo[4],
                  w5 = wo[5], w6 = wo[6], w7 = wo[7], w8 = wo[8];
            #pragma unroll
            for (int j = 0; j < 4; j++) {
                acc[o][j] += w0 * a[0][j] + w1 * a[0][j+1] + w2 * a[0][j+2]
                           + w3 * a[1][j] + w4 * a[1][j+1] + w5 * a[1][j+2]
                           + w6 * a[2][j] + w7 * a[2][j+1] + w8 * a[2][j+2];
            }
        }
    }
    int oc0 = ocg * OCB;
    #pragma unroll
    for (int o = 0; o < OCB; o++) {
        float d  = d1[b * 256 + oc0 + o];
        float nz = n1[b * 256 + oc0 + o];
        float4 v;
        float t;
        t = acc[o][0] * d + nz; v.x = (t >= 0.f) ? t : 0.1f * t;
        t = acc[o][1] * d + nz; v.y = (t >= 0.f) ? t : 0.1f * t;
        t = acc[o][2] * d + nz; v.z = (t >= 0.f) ? t : 0.1f * t;
        t = acc[o][3] * d + nz; v.w = (t >= 0.f) ? t : 0.1f * t;
        *(float4*)&y1[(((size_t)b * C1 + oc0 + o) << 12) + ((y0 + ty) << 6) + x0 + tx4] = v;
    }
}

// ------- conv2: fused bilinear 2x upsample + modulated 3x3, 256->128 @128x128 -------
__global__ __launch_bounds__(256)
void conv2_kernel(const float* __restrict__ y1, const float* __restrict__ cw,
                  const float* __restrict__ s2, const float* __restrict__ d2,
                  const float* __restrict__ n2, float* __restrict__ out) {
    __shared__ __align__(16) float src[18 * SSTR];
    __shared__ __align__(16) float up[34 * ISTR];
    int b    = blockIdx.z;
    int ocg  = blockIdx.y;              // 0..7
    int tile = blockIdx.x;              // 0..15
    int y0 = (tile >> 2) * TS;
    int x0 = (tile & 3) * TS;
    int orgy = (y0 >> 1) - 1;
    int orgx = (x0 >> 1) - 1;
    int tid = threadIdx.x;
    int ty  = tid >> 3;
    int tx4 = (tid & 7) << 2;

    float acc[OCB][4];
    #pragma unroll
    for (int o = 0; o < OCB; o++)
        #pragma unroll
        for (int j = 0; j < 4; j++) acc[o][j] = 0.f;

    const float* sb = s2 + b * 256;
    for (int ic = 0; ic < C1; ic++) {
        __syncthreads();
        float sv = sb[ic];
        const float* xp = y1 + (((size_t)b * C1 + ic) << 12);
        // stage 18x18 source patch (edge-clamped), styles folded in
        for (int e = tid; e < 18 * 18; e += 256) {
            int r = e / 18, c = e % 18;
            int gy = clampi(orgy + r, 0, 63);
            int gx = clampi(orgx + c, 0, 63);
            src[r * SSTR + c] = xp[(gy << 6) + gx] * sv;
        }
        __syncthreads();
        // build 34x34 upsampled patch (zero-padded for the conv)
        for (int e = tid; e < 34 * 34; e += 256) {
            int r = e / 34, c = e % 34;
            int uy = y0 - 1 + r, ux = x0 - 1 + c;
            float v = 0.f;
            if (uy >= 0 && uy < 128 && ux >= 0 && ux < 128) {
                int jyA; float wyA;
                if (uy & 1) { jyA = uy >> 1;       wyA = 0.75f; }
                else        { jyA = (uy >> 1) - 1; wyA = 0.25f; }
                int jxA; float wxA;
                if (ux & 1) { jxA = ux >> 1;       wxA = 0.75f; }
                else        { jxA = (ux >> 1) - 1; wxA = 0.25f; }
                int pA = clampi(jyA,     0, 63) - orgy;
                int pB = clampi(jyA + 1, 0, 63) - orgy;
                int qA = clampi(jxA,     0, 63) - orgx;
                int qB = clampi(jxA + 1, 0, 63) - orgx;
                float wyB = 1.f - wyA, wxB = 1.f - wxA;
                v = wyA * (wxA * src[pA * SSTR + qA] + wxB * src[pA * SSTR + qB])
                  + wyB * (wxA * src[pB * SSTR + qA] + wxB * src[pB * SSTR + qB]);
            }
            up[r * ISTR + c] = v;
        }
        __syncthreads();
        float a[3][6];
        #pragma unroll
        for (int kh = 0; kh < 3; kh++) {
            const float* p = &up[(ty + kh) * ISTR + tx4];
            #pragma unroll
            for (int c = 0; c < 6; c++) a[kh][c] = p[c];
        }
        const float* wp = cw + ((size_t)(ocg * OCB) * C1 + ic) * 9;
        #pragma unroll
        for (int o = 0; o < OCB; o++) {
            const float* wo = wp + (size_t)o * C1 * 9;
            float w0 = wo[0], w1 = wo[1], w2 = wo[2], w3 = wo[3], w4 = wo[4],
                  w5 = wo[5], w6 = wo[6], w7 = wo[7], w8 = wo[8];
            #pragma unroll
            for (int j = 0; j < 4; j++) {
                acc[o][j] += w0 * a[0][j] + w1 * a[0][j+1] + w2 * a[0][j+2]
                           + w3 * a[1][j] + w4 * a[1][j+1] + w5 * a[1][j+2]
                           + w6 * a[2][j] + w7 * a[2][j+1] + w8 * a[2][j+2];
            }
        }
    }
    int oc0 = ocg * OCB;
    #pragma unroll
    for (int o = 0; o < OCB; o++) {
        float d  = d2[b * 128 + oc0 + o];
        float nz = n2[b * 128 + oc0 + o];
        float4 v;
        float t;
        t = acc[o][0] * d + nz; v.x = (t >= 0.f) ? t : 0.1f * t;
        t = acc[o][1] * d + nz; v.y = (t >= 0.f) ? t : 0.1f * t;
        t = acc[o][2] * d + nz; v.z = (t >= 0.f) ? t : 0.1f * t;
        t = acc[o][3] * d + nz; v.w = (t >= 0.f) ? t : 0.1f * t;
        *(float4*)&out[(((size_t)b * C2 + oc0 + o) << 14) + ((y0 + ty) << 7) + x0 + tx4] = v;
    }
}

// ---------------- toRGB: 1x1 conv + bilinear-upsampled residual ----------------
__global__ __launch_bounds__(256)
void torgb_kernel(const float* __restrict__ xo, const float* __restrict__ rgb,
                  const float* __restrict__ rw, const float* __restrict__ rb,
                  float* __restrict__ out) {
    int b  = blockIdx.y;
    int rp = blockIdx.x;                 // 0..63 (row pairs)
    int tid = threadIdx.x;
    int y = rp * 2 + (tid >> 7);
    int x = tid & 127;
    const float* xp = xo + (((size_t)b * C2) << 14) + (y << 7) + x;
    float a0 = rb[0], a1 = rb[1], a2 = rb[2];
    for (int o = 0; o < C2; o++) {
        float v = xp[(size_t)o << 14];
        a0 += rw[o] * v;
        a1 += rw[128 + o] * v;
        a2 += rw[256 + o] * v;
    }
    int jyA; float wyA;
    if (y & 1) { jyA = y >> 1;       wyA = 0.75f; }
    else       { jyA = (y >> 1) - 1; wyA = 0.25f; }
    int jxA; float wxA;
    if (x & 1) { jxA = x >> 1;       wxA = 0.75f; }
    else       { jxA = (x >> 1) - 1; wxA = 0.25f; }
    int yA = clampi(jyA, 0, 63), yB = clampi(jyA + 1, 0, 63);
    int xA = clampi(jxA, 0, 63), xB = clampi(jxA + 1, 0, 63);
    float wyB = 1.f - wyA, wxB = 1.f - wxA;
    const float* rp3 = rgb + (((size_t)b * 3) << 12);
    float res[3] = {a0, a1, a2};
    #pragma unroll
    for (int c = 0; c < 3; c++) {
        const float* rc = rp3 + ((size_t)c << 12);
        float u = wyA * (wxA * rc[(yA << 6) + xA] + wxB * rc[(yA << 6) + xB])
                + wyB * (wxA * rc[(yB << 6) + xA] + wxB * rc[(yB << 6) + xB]);
        out[(((size_t)b * 3 + c) << 14) + (y << 7) + x] = (res[c] + u) * 0.70710678118654752f;
    }
}

extern "C" void kernel_launch(void* const* d_in, const int* in_sizes, int n_in,
                              void* d_out, int out_size, void* d_ws, size_t ws_size,
                              hipStream_t stream) {
    (void)in_sizes; (void)n_in; (void)out_size; (void)ws_size;
    const float* x     = (const float*)d_in[0];
    const float* w     = (const float*)d_in[1];
    const float* n     = (const float*)d_in[2];
    const float* rgb   = (const float*)d_in[3];
    const float* cw1   = (const float*)d_in[4];
    const float* A1w   = (const float*)d_in[5];
    const float* A1b   = (const float*)d_in[6];
    const float* B1w   = (const float*)d_in[7];
    const float* B1b   = (const float*)d_in[8];
    const float* cw2   = (const float*)d_in[9];
    const float* A2w   = (const float*)d_in[10];
    const float* A2b   = (const float*)d_in[11];
    const float* B2w   = (const float*)d_in[12];
    const float* B2b   = (const float*)d_in[13];
    const float* rgbw  = (const float*)d_in[14];
    const float* rgbb  = (const float*)d_in[15];

    float* ws = (float*)d_ws;
    float* s1 = ws;            // 2048
    float* s2 = ws + 2048;     // 2048
    float* d1 = ws + 4096;     // 2048
    float* d2 = ws + 6144;     // 1024
    float* n1 = ws + 7168;     // 2048
    float* n2 = ws + 9216;     // 1024
    float* y1 = ws + 10240;    // 8*256*64*64 = 8388608  (~33.6 MB total ws use)

    float* xout = (float*)d_out;                 // 8*128*128*128
    float* rgbo = xout + (size_t)BN * C2 * H2 * H2;

    affine_kernel<<<(BN * 896 + 255) / 256, 256, 0, stream>>>(
        w, n, A1w, A1b, B1w, B1b, A2w, A2b, B2w, B2b, s1, s2, n1, n2);
    demod_kernel<<<(BN * 384 + 255) / 256, 256, 0, stream>>>(cw1, cw2, s1, s2, d1, d2);
    conv1_kernel<<<dim3(4, 16, BN), 256, 0, stream>>>(x, cw1, s1, d1, n1, y1);
    conv2_kernel<<<dim3(16, 8, BN), 256, 0, stream>>>(y1, cw2, s2, d2, n2, xout);
    torgb_kernel<<<dim3(64, BN), 256, 0, stream>>>(xout, rgb, rgbw, rgbb, rgbo);
}

// Round 3
// 579.204 us; speedup vs baseline: 7.0139x; 7.0139x over previous
//
#include <hip/hip_runtime.h>
#include <math.h>

#define BN 8
#define C1 256
#define C2 128
#define WD 512

typedef float  f32x4  __attribute__((ext_vector_type(4)));
typedef short  bf16x8 __attribute__((ext_vector_type(8)));
typedef unsigned short ushort_t;
typedef ushort_t us8 __attribute__((ext_vector_type(8)));
typedef ushort_t us4 __attribute__((ext_vector_type(4)));

__device__ __forceinline__ int clampi(int v, int lo, int hi) {
    return v < lo ? lo : (v > hi ? hi : v);
}
__device__ __forceinline__ float bf2f(ushort_t u) {
    return __uint_as_float(((unsigned int)u) << 16);
}
__device__ __forceinline__ ushort_t f2bf(float f) {
    unsigned int u = __float_as_uint(f);
    u = (u + 0x7fff + ((u >> 16) & 1)) >> 16;   // RNE
    return (ushort_t)u;
}

// ---------------- affine (wave-per-output): s1, s2, n1, n2 ----------------
__global__ __launch_bounds__(256)
void affine_kernel(const float* __restrict__ w, const float* __restrict__ n,
                   const float* __restrict__ A1w, const float* __restrict__ A1b,
                   const float* __restrict__ B1w, const float* __restrict__ B1b,
                   const float* __restrict__ A2w, const float* __restrict__ A2b,
                   const float* __restrict__ B2w, const float* __restrict__ B2b,
                   float* __restrict__ s1, float* __restrict__ s2,
                   float* __restrict__ n1, float* __restrict__ n2) {
    int tid = threadIdx.x;
    int gw = blockIdx.x * 4 + (tid >> 6);   // global wave id, 0..7167
    int lane = tid & 63;
    if (gw >= BN * 896) return;
    int b = gw / 896;
    int j = gw % 896;
    const float* vec; const float* M; const float* bias; float* out; int o;
    if (j < 256)      { o = j;       vec = w + b * WD; M = A1w; bias = A1b; out = s1 + b * 256; }
    else if (j < 512) { o = j - 256; vec = w + b * WD; M = A2w; bias = A2b; out = s2 + b * 256; }
    else if (j < 768) { o = j - 512; vec = n + b * WD; M = B1w; bias = B1b; out = n1 + b * 256; }
    else              { o = j - 768; vec = n + b * WD; M = B2w; bias = B2b; out = n2 + b * 128; }
    const float* row = M + (size_t)o * WD;
    int k0 = lane * 8;
    float4 v0 = *(const float4*)(vec + k0), v1 = *(const float4*)(vec + k0 + 4);
    float4 r0 = *(const float4*)(row + k0), r1 = *(const float4*)(row + k0 + 4);
    float acc = v0.x*r0.x + v0.y*r0.y + v0.z*r0.z + v0.w*r0.w
              + v1.x*r1.x + v1.y*r1.y + v1.z*r1.z + v1.w*r1.w;
    #pragma unroll
    for (int m = 1; m < 64; m <<= 1) acc += __shfl_xor(acc, m, 64);
    if (lane == 0) out[o] = acc + bias[o];
}

// ---------------- demod (wave-per-output) ----------------
__global__ __launch_bounds__(256)
void demod_kernel(const float* __restrict__ cw1, const float* __restrict__ cw2,
                  const float* __restrict__ s1, const float* __restrict__ s2,
                  float* __restrict__ d1, float* __restrict__ d2) {
    int tid = threadIdx.x;
    int gw = blockIdx.x * 4 + (tid >> 6);   // 0..3071
    int lane = tid & 63;
    if (gw >= BN * 384) return;
    int b = gw / 384;
    int j = gw % 384;
    const float* wbase; const float* s; float* dout; int o;
    if (j < 256) { o = j;       wbase = cw1; s = s1 + b * 256; dout = d1 + b * 256; }
    else         { o = j - 256; wbase = cw2; s = s2 + b * 256; dout = d2 + b * 128; }
    float acc = 0.f;
    #pragma unroll
    for (int i = 0; i < 4; i++) {
        int ic = lane * 4 + i;
        float sv = s[ic]; sv *= sv;
        const float* wk = wbase + ((size_t)o * 256 + ic) * 9;
        float t = 0.f;
        #pragma unroll
        for (int k = 0; k < 9; k++) t += wk[k] * wk[k];
        acc += t * sv;
    }
    #pragma unroll
    for (int m = 1; m < 64; m <<= 1) acc += __shfl_xor(acc, m, 64);
    if (lane == 0) dout[o] = rsqrtf(acc + 1e-5f);
}

// ---------------- weight transpose -> bf16: wT[tap][oc][ic] ----------------
__global__ __launch_bounds__(256)
void wprep_kernel(const float* __restrict__ cw1, const float* __restrict__ cw2,
                  ushort_t* __restrict__ wT1, ushort_t* __restrict__ wT2) {
    int idx = blockIdx.x * 256 + threadIdx.x;
    if (idx < 9 * 256 * 256) {
        int tap = idx >> 16;
        int oc = (idx >> 8) & 255;
        int ic = idx & 255;
        wT1[idx] = f2bf(cw1[((size_t)(oc * 256 + ic)) * 9 + tap]);
    } else if (idx < 9 * 256 * 256 + 9 * 128 * 256) {
        int e = idx - 9 * 256 * 256;
        int tap = e >> 15;
        int oc = (e >> 8) & 127;
        int ic = e & 255;
        wT2[e] = f2bf(cw2[((size_t)(oc * 256 + ic)) * 9 + tap]);
    }
}

// -------- xprep: x[b][ic][y][x] f32 -> xTp[b][66][66][256] bf16, styles folded --------
__global__ __launch_bounds__(512)
void xprep_kernel(const float* __restrict__ x, const float* __restrict__ s1,
                  ushort_t* __restrict__ xTp) {
    int tid = threadIdx.x;
    int b = blockIdx.y;
    int px_lin = blockIdx.x * 16 + (tid >> 5);   // 0..4095
    int ic8 = tid & 31;
    int gy = px_lin >> 6, gx = px_lin & 63;
    const float* xb = x + (((size_t)b * C1) << 12) + (gy << 6) + gx;
    float4 slo = *(const float4*)(s1 + b * 256 + ic8 * 8);
    float4 shi = *(const float4*)(s1 + b * 256 + ic8 * 8 + 4);
    float sv[8] = {slo.x, slo.y, slo.z, slo.w, shi.x, shi.y, shi.z, shi.w};
    us8 h;
    #pragma unroll
    for (int j = 0; j < 8; j++) {
        float v = xb[((size_t)(ic8 * 8 + j)) << 12];
        h[j] = f2bf(v * sv[j]);
    }
    *(us8*)(xTp + (size_t)b * 66 * 66 * 256 + ((size_t)(gy + 1) * 66 + gx + 1) * 256 + ic8 * 8) = h;
}

// -------- upsample: y1T[b][64][64][256] -> y1up[b][130][130][256], *s2 folded --------
__global__ __launch_bounds__(256)
void upsample_kernel(const ushort_t* __restrict__ y1T, const float* __restrict__ s2,
                     ushort_t* __restrict__ y1up) {
    int flat = blockIdx.x * 256 + threadIdx.x;    // 0..524287
    int b = blockIdx.y;
    int ic8 = flat & 31;
    int pxl = flat >> 5;
    int ux = pxl & 127, uy = pxl >> 7;
    int jyA; float wyA;
    if (uy & 1) { jyA = uy >> 1;       wyA = 0.75f; }
    else        { jyA = (uy >> 1) - 1; wyA = 0.25f; }
    int jxA; float wxA;
    if (ux & 1) { jxA = ux >> 1;       wxA = 0.75f; }
    else        { jxA = (ux >> 1) - 1; wxA = 0.25f; }
    int yA = clampi(jyA, 0, 63), yB = clampi(jyA + 1, 0, 63);
    int xA = clampi(jxA, 0, 63), xB = clampi(jxA + 1, 0, 63);
    float wyB = 1.f - wyA, wxB = 1.f - wxA;
    const ushort_t* yb = y1T + (size_t)b * 64 * 64 * 256 + ic8 * 8;
    us8 qAA = *(const us8*)(yb + (size_t)(yA * 64 + xA) * 256);
    us8 qAB = *(const us8*)(yb + (size_t)(yA * 64 + xB) * 256);
    us8 qBA = *(const us8*)(yb + (size_t)(yB * 64 + xA) * 256);
    us8 qBB = *(const us8*)(yb + (size_t)(yB * 64 + xB) * 256);
    float4 slo = *(const float4*)(s2 + b * 256 + ic8 * 8);
    float4 shi = *(const float4*)(s2 + b * 256 + ic8 * 8 + 4);
    float sv[8] = {slo.x, slo.y, slo.z, slo.w, shi.x, shi.y, shi.z, shi.w};
    us8 h;
    #pragma unroll
    for (int j = 0; j < 8; j++) {
        float v = wyA * (wxA * bf2f(qAA[j]) + wxB * bf2f(qAB[j]))
                + wyB * (wxA * bf2f(qBA[j]) + wxB * bf2f(qBB[j]));
        h[j] = f2bf(v * sv[j]);
    }
    *(us8*)(y1up + (size_t)b * 130 * 130 * 256 + ((size_t)(uy + 1) * 130 + ux + 1) * 256 + ic8 * 8) = h;
}

// ---------------- conv1 MFMA: 256->256 @64x64, out tile 16x16 px, 64 oc ----------------
__global__ __launch_bounds__(256, 3)
void conv1_mfma(const ushort_t* __restrict__ xTp, const ushort_t* __restrict__ wT1,
                const float* __restrict__ d1, const float* __restrict__ n1,
                ushort_t* __restrict__ y1T) {
    __shared__ __align__(16) ushort_t lbuf[2][10368];   // 18*18*32 bf16 per buffer
    int b = blockIdx.z, ocg = blockIdx.y, tile = blockIdx.x;
    int ty0 = (tile >> 2) * 16, tx0 = (tile & 3) * 16;
    int tid = threadIdx.x, lane = tid & 63, wave = tid >> 6;
    int col = lane & 15, quad = lane >> 4;
    const ushort_t* xb = xTp + (size_t)b * 66 * 66 * 256;

    f32x4 acc[4][4];
    #pragma unroll
    for (int mt = 0; mt < 4; mt++)
        #pragma unroll
        for (int nt = 0; nt < 4; nt++) acc[mt][nt] = (f32x4)(0.f);

#define STAGE1(KC, BUFI) { \
    int kb = (KC) * 32; \
    _Pragma("unroll") \
    for (int r = 0; r < 6; r++) { \
        int flatB = (r * 256 + tid) * 16; \
        if (flatB < 20736) { \
            int pxl = flatB >> 6; int ics = (flatB & 63) >> 1; \
            int py = pxl / 18, px = pxl - py * 18; \
            const ushort_t* g = xb + ((size_t)(ty0 + py) * 66 + (tx0 + px)) * 256 + kb + ics; \
            *(us8*)((char*)lbuf[BUFI] + flatB) = *(const us8*)g; \
        } } }

    STAGE1(0, 0);
    __syncthreads();
    for (int kc = 0; kc < 8; kc++) {
        int cur = kc & 1;
        if (kc < 7) STAGE1(kc + 1, cur ^ 1);
        const ushort_t* lb = lbuf[cur];
        #pragma unroll
        for (int tap = 0; tap < 9; tap++) {
            const int dy = tap / 3, dx = tap % 3;
            bf16x8 a[4], bb[4];
            #pragma unroll
            for (int mt = 0; mt < 4; mt++)
                a[mt] = *(const bf16x8*)(wT1 + (((size_t)tap * 256 + ocg * 64 + mt * 16 + col) * 256 + kc * 32 + quad * 8));
            #pragma unroll
            for (int nt = 0; nt < 4; nt++) {
                int ry = wave * 4 + nt;
                bb[nt] = *(const bf16x8*)((const char*)lb + (((ry + dy) * 18 + col + dx) << 6) + (quad << 4));
            }
            #pragma unroll
            for (int mt = 0; mt < 4; mt++)
                #pragma unroll
                for (int nt = 0; nt < 4; nt++)
                    acc[mt][nt] = __builtin_amdgcn_mfma_f32_16x16x32_bf16(a[mt], bb[nt], acc[mt][nt], 0, 0, 0);
        }
        __syncthreads();
    }
#undef STAGE1

    #pragma unroll
    for (int mt = 0; mt < 4; mt++) {
        int oc0 = ocg * 64 + mt * 16 + quad * 4;
        float4 dv = *(const float4*)(d1 + b * 256 + oc0);
        float4 nv = *(const float4*)(n1 + b * 256 + oc0);
        float dva[4] = {dv.x, dv.y, dv.z, dv.w};
        float nva[4] = {nv.x, nv.y, nv.z, nv.w};
        #pragma unroll
        for (int nt = 0; nt < 4; nt++) {
            int gy = ty0 + wave * 4 + nt, gx = tx0 + col;
            us4 h;
            #pragma unroll
            for (int r = 0; r < 4; r++) {
                float t = acc[mt][nt][r] * dva[r] + nva[r];
                t = (t >= 0.f) ? t : 0.1f * t;
                h[r] = f2bf(t);
            }
            // FIX: batch offset was missing here (all batches wrote slot 0)
            *(us4*)(y1T + (size_t)b * 64 * 64 * 256 + (size_t)(gy * 64 + gx) * 256 + oc0) = h;
        }
    }
}

// ------- conv2 MFMA: 256->128 @128x128 (upsampled input), tile 16x8 px, 128 oc, +toRGB -------
__global__ __launch_bounds__(256, 3)
void conv2_mfma(const ushort_t* __restrict__ y1up, const ushort_t* __restrict__ wT2,
                const float* __restrict__ d2, const float* __restrict__ n2,
                const float* __restrict__ rgb_in, const float* __restrict__ rw,
                const float* __restrict__ rb,
                float* __restrict__ xout, float* __restrict__ rgbo) {
    __shared__ __align__(16) ushort_t lbuf[2][5760];    // 10*18*32 bf16 per buffer
    __shared__ float rgbacc[8][16][3];
    int b = blockIdx.y, tile = blockIdx.x;
    int ty0 = (tile >> 3) * 8, tx0 = (tile & 7) * 16;
    int tid = threadIdx.x, lane = tid & 63, wave = tid >> 6;
    int col = lane & 15, quad = lane >> 4;
    int mh = wave >> 1, ng = wave & 1;
    const ushort_t* xb = y1up + (size_t)b * 130 * 130 * 256;

    for (int i = tid; i < 8 * 16 * 3; i += 256) ((float*)rgbacc)[i] = 0.f;

    f32x4 acc[4][4];
    #pragma unroll
    for (int mt = 0; mt < 4; mt++)
        #pragma unroll
        for (int nt = 0; nt < 4; nt++) acc[mt][nt] = (f32x4)(0.f);

#define STAGE2(KC, BUFI) { \
    int kb = (KC) * 32; \
    _Pragma("unroll") \
    for (int r = 0; r < 3; r++) { \
        int flatB = (r * 256 + tid) * 16; \
        if (flatB < 11520) { \
            int pxl = flatB >> 6; int ics = (flatB & 63) >> 1; \
            int py = pxl / 18, px = pxl - py * 18; \
            const ushort_t* g = xb + ((size_t)(ty0 + py) * 130 + (tx0 + px)) * 256 + kb + ics; \
            *(us8*)((char*)lbuf[BUFI] + flatB) = *(const us8*)g; \
        } } }

    STAGE2(0, 0);
    __syncthreads();
    for (int kc = 0; kc < 8; kc++) {
        int cur = kc & 1;
        if (kc < 7) STAGE2(kc + 1, cur ^ 1);
        const ushort_t* lb = lbuf[cur];
        #pragma unroll
        for (int tap = 0; tap < 9; tap++) {
            const int dy = tap / 3, dx = tap % 3;
            bf16x8 a[4], bb[4];
            #pragma unroll
            for (int mt = 0; mt < 4; mt++)
                a[mt] = *(const bf16x8*)(wT2 + (((size_t)tap * 128 + mh * 64 + mt * 16 + col) * 256 + kc * 32 + quad * 8));
            #pragma unroll
            for (int nt = 0; nt < 4; nt++) {
                int ry = ng * 4 + nt;
                bb[nt] = *(const bf16x8*)((const char*)lb + (((ry + dy) * 18 + col + dx) << 6) + (quad << 4));
            }
            #pragma unroll
            for (int mt = 0; mt < 4; mt++)
                #pragma unroll
                for (int nt = 0; nt < 4; nt++)
                    acc[mt][nt] = __builtin_amdgcn_mfma_f32_16x16x32_bf16(a[mt], bb[nt], acc[mt][nt], 0, 0, 0);
        }
        __syncthreads();
    }
#undef STAGE2

    // epilogue: demod + noise + leaky, write x (NCHW f32), accumulate rgb partials
    float dva[4][4], nva[4][4], rwa[3][4][4];
    #pragma unroll
    for (int mt = 0; mt < 4; mt++) {
        int oc0 = mh * 64 + mt * 16 + quad * 4;
        float4 dv = *(const float4*)(d2 + b * 128 + oc0);
        float4 nv = *(const float4*)(n2 + b * 128 + oc0);
        dva[mt][0] = dv.x; dva[mt][1] = dv.y; dva[mt][2] = dv.z; dva[mt][3] = dv.w;
        nva[mt][0] = nv.x; nva[mt][1] = nv.y; nva[mt][2] = nv.z; nva[mt][3] = nv.w;
        #pragma unroll
        for (int c = 0; c < 3; c++) {
            float4 rv = *(const float4*)(rw + c * 128 + oc0);
            rwa[c][mt][0] = rv.x; rwa[c][mt][1] = rv.y; rwa[c][mt][2] = rv.z; rwa[c][mt][3] = rv.w;
        }
    }
    #pragma unroll
    for (int nt = 0; nt < 4; nt++) {
        int row = ng * 4 + nt;
        int uy = ty0 + row, ux = tx0 + col;
        float pc0 = 0.f, pc1 = 0.f, pc2 = 0.f;
        #pragma unroll
        for (int mt = 0; mt < 4; mt++) {
            int oc0 = mh * 64 + mt * 16 + quad * 4;
            #pragma unroll
            for (int r = 0; r < 4; r++) {
                float t = acc[mt][nt][r] * dva[mt][r] + nva[mt][r];
                t = (t >= 0.f) ? t : 0.1f * t;
                xout[(((size_t)b * 128 + oc0 + r) << 14) + (uy << 7) + ux] = t;
                pc0 += rwa[0][mt][r] * t;
                pc1 += rwa[1][mt][r] * t;
                pc2 += rwa[2][mt][r] * t;
            }
        }
        atomicAdd(&rgbacc[row][col][0], pc0);
        atomicAdd(&rgbacc[row][col][1], pc1);
        atomicAdd(&rgbacc[row][col][2], pc2);
    }
    __syncthreads();

    if (tid < 128) {
        int row = tid >> 4, c2 = tid & 15;
        int uy = ty0 + row, ux = tx0 + c2;
        int jyA; float wyA;
        if (uy & 1) { jyA = uy >> 1;       wyA = 0.75f; }
        else        { jyA = (uy >> 1) - 1; wyA = 0.25f; }
        int jxA; float wxA;
        if (ux & 1) { jxA = ux >> 1;       wxA = 0.75f; }
        else        { jxA = (ux >> 1) - 1; wxA = 0.25f; }
        int yA = clampi(jyA, 0, 63), yB = clampi(jyA + 1, 0, 63);
        int xA = clampi(jxA, 0, 63), xB = clampi(jxA + 1, 0, 63);
        float wyB = 1.f - wyA, wxB = 1.f - wxA;
        const float* rp3 = rgb_in + (((size_t)b * 3) << 12);
        #pragma unroll
        for (int c = 0; c < 3; c++) {
            const float* rc = rp3 + ((size_t)c << 12);
            float u = wyA * (wxA * rc[(yA << 6) + xA] + wxB * rc[(yA << 6) + xB])
                    + wyB * (wxA * rc[(yB << 6) + xA] + wxB * rc[(yB << 6) + xB]);
            float v = rgbacc[row][c2][c] + rb[c] + u;
            rgbo[(((size_t)b * 3 + c) << 14) + (uy << 7) + ux] = v * 0.70710678118654752f;
        }
    }
}

extern "C" void kernel_launch(void* const* d_in, const int* in_sizes, int n_in,
                              void* d_out, int out_size, void* d_ws, size_t ws_size,
                              hipStream_t stream) {
    (void)in_sizes; (void)n_in; (void)out_size; (void)ws_size;
    const float* x     = (const float*)d_in[0];
    const float* w     = (const float*)d_in[1];
    const float* n     = (const float*)d_in[2];
    const float* rgb   = (const float*)d_in[3];
    const float* cw1   = (const float*)d_in[4];
    const float* A1w   = (const float*)d_in[5];
    const float* A1b   = (const float*)d_in[6];
    const float* B1w   = (const float*)d_in[7];
    const float* B1b   = (const float*)d_in[8];
    const float* cw2   = (const float*)d_in[9];
    const float* A2w   = (const float*)d_in[10];
    const float* A2b   = (const float*)d_in[11];
    const float* B2w   = (const float*)d_in[12];
    const float* B2b   = (const float*)d_in[13];
    const float* rgbw  = (const float*)d_in[14];
    const float* rgbb  = (const float*)d_in[15];

    char* ws = (char*)d_ws;
    float* s1 = (float*)(ws);            // 8 KB
    float* s2 = (float*)(ws + 8192);
    float* d1 = (float*)(ws + 16384);
    float* d2 = (float*)(ws + 24576);
    float* n1 = (float*)(ws + 28672);
    float* n2 = (float*)(ws + 36864);
    ushort_t* wT1  = (ushort_t*)(ws + 40960);          // 1179648 B
    ushort_t* wT2  = (ushort_t*)(ws + 1220608);        // 589824 B
    ushort_t* xTp  = (ushort_t*)(ws + 1810432);        // 17842176 B
    ushort_t* y1up = (ushort_t*)(ws + 19652608);       // 69222400 B
    ushort_t* y1T  = (ushort_t*)(ws + 88875008);       // 16777216 B (total ~100.8 MiB)

    float* xout = (float*)d_out;
    float* rgbo = xout + (size_t)BN * C2 * 128 * 128;

    // zero the padded buffers (xTp + y1up are contiguous)
    hipMemsetAsync(xTp, 0, 17842176 + 69222400, stream);

    affine_kernel<<<1792, 256, 0, stream>>>(w, n, A1w, A1b, B1w, B1b, A2w, A2b, B2w, B2b,
                                            s1, s2, n1, n2);
    demod_kernel<<<768, 256, 0, stream>>>(cw1, cw2, s1, s2, d1, d2);
    wprep_kernel<<<(9 * 256 * 256 + 9 * 128 * 256 + 255) / 256, 256, 0, stream>>>(cw1, cw2, wT1, wT2);
    xprep_kernel<<<dim3(256, BN), 512, 0, stream>>>(x, s1, xTp);
    conv1_mfma<<<dim3(16, 4, BN), 256, 0, stream>>>(xTp, wT1, d1, n1, y1T);
    upsample_kernel<<<dim3(2048, BN), 256, 0, stream>>>(y1T, s2, y1up);
    conv2_mfma<<<dim3(128, BN), 256, 0, stream>>>(y1up, wT2, d2, n2, rgb, rgbw, rgbb,
                                                  xout, rgbo);
}

// Round 5
// 310.829 us; speedup vs baseline: 13.0698x; 1.8634x over previous
//
#include <hip/hip_runtime.h>
#include <math.h>

#define BN 8
#define C1 256
#define C2 128
#define WD 512

typedef float  f32x4  __attribute__((ext_vector_type(4)));
typedef short  bf16x8 __attribute__((ext_vector_type(8)));
typedef unsigned short ushort_t;
typedef ushort_t us8 __attribute__((ext_vector_type(8)));
typedef ushort_t us4 __attribute__((ext_vector_type(4)));

__device__ __forceinline__ int clampi(int v, int lo, int hi) {
    return v < lo ? lo : (v > hi ? hi : v);
}
__device__ __forceinline__ float bf2f(ushort_t u) {
    return __uint_as_float(((unsigned int)u) << 16);
}
__device__ __forceinline__ ushort_t f2bf(float f) {
    unsigned int u = __float_as_uint(f);
    u = (u + 0x7fff + ((u >> 16) & 1)) >> 16;   // RNE
    return (ushort_t)u;
}

// ---------------- affine (wave-per-output): s1, s2, n1, n2 ----------------
__global__ __launch_bounds__(256)
void affine_kernel(const float* __restrict__ w, const float* __restrict__ n,
                   const float* __restrict__ A1w, const float* __restrict__ A1b,
                   const float* __restrict__ B1w, const float* __restrict__ B1b,
                   const float* __restrict__ A2w, const float* __restrict__ A2b,
                   const float* __restrict__ B2w, const float* __restrict__ B2b,
                   float* __restrict__ s1, float* __restrict__ s2,
                   float* __restrict__ n1, float* __restrict__ n2) {
    int tid = threadIdx.x;
    int gw = blockIdx.x * 4 + (tid >> 6);
    int lane = tid & 63;
    if (gw >= BN * 896) return;
    int b = gw / 896;
    int j = gw % 896;
    const float* vec; const float* M; const float* bias; float* out; int o;
    if (j < 256)      { o = j;       vec = w + b * WD; M = A1w; bias = A1b; out = s1 + b * 256; }
    else if (j < 512) { o = j - 256; vec = w + b * WD; M = A2w; bias = A2b; out = s2 + b * 256; }
    else if (j < 768) { o = j - 512; vec = n + b * WD; M = B1w; bias = B1b; out = n1 + b * 256; }
    else              { o = j - 768; vec = n + b * WD; M = B2w; bias = B2b; out = n2 + b * 128; }
    const float* row = M + (size_t)o * WD;
    int k0 = lane * 8;
    float4 v0 = *(const float4*)(vec + k0), v1 = *(const float4*)(vec + k0 + 4);
    float4 r0 = *(const float4*)(row + k0), r1 = *(const float4*)(row + k0 + 4);
    float acc = v0.x*r0.x + v0.y*r0.y + v0.z*r0.z + v0.w*r0.w
              + v1.x*r1.x + v1.y*r1.y + v1.z*r1.z + v1.w*r1.w;
    #pragma unroll
    for (int m = 1; m < 64; m <<= 1) acc += __shfl_xor(acc, m, 64);
    if (lane == 0) out[o] = acc + bias[o];
}

// ---------------- demod (wave-per-output) ----------------
__global__ __launch_bounds__(256)
void demod_kernel(const float* __restrict__ cw1, const float* __restrict__ cw2,
                  const float* __restrict__ s1, const float* __restrict__ s2,
                  float* __restrict__ d1, float* __restrict__ d2) {
    int tid = threadIdx.x;
    int gw = blockIdx.x * 4 + (tid >> 6);
    int lane = tid & 63;
    if (gw >= BN * 384) return;
    int b = gw / 384;
    int j = gw % 384;
    const float* wbase; const float* s; float* dout; int o;
    if (j < 256) { o = j;       wbase = cw1; s = s1 + b * 256; dout = d1 + b * 256; }
    else         { o = j - 256; wbase = cw2; s = s2 + b * 256; dout = d2 + b * 128; }
    float acc = 0.f;
    #pragma unroll
    for (int i = 0; i < 4; i++) {
        int ic = lane * 4 + i;
        float sv = s[ic]; sv *= sv;
        const float* wk = wbase + ((size_t)o * 256 + ic) * 9;
        float t = 0.f;
        #pragma unroll
        for (int k = 0; k < 9; k++) t += wk[k] * wk[k];
        acc += t * sv;
    }
    #pragma unroll
    for (int m = 1; m < 64; m <<= 1) acc += __shfl_xor(acc, m, 64);
    if (lane == 0) dout[o] = rsqrtf(acc + 1e-5f);
}

// ---------------- weight transpose -> bf16: wT[tap][oc][ic] ----------------
__global__ __launch_bounds__(256)
void wprep_kernel(const float* __restrict__ cw1, const float* __restrict__ cw2,
                  ushort_t* __restrict__ wT1, ushort_t* __restrict__ wT2) {
    int idx = blockIdx.x * 256 + threadIdx.x;
    if (idx < 9 * 256 * 256) {
        int tap = idx >> 16;
        int oc = (idx >> 8) & 255;
        int ic = idx & 255;
        wT1[idx] = f2bf(cw1[((size_t)(oc * 256 + ic)) * 9 + tap]);
    } else if (idx < 9 * 256 * 256 + 9 * 128 * 256) {
        int e = idx - 9 * 256 * 256;
        int tap = e >> 15;
        int oc = (e >> 8) & 127;
        int ic = e & 255;
        wT2[e] = f2bf(cw2[((size_t)(oc * 256 + ic)) * 9 + tap]);
    }
}

// -------- xprep: x[b][ic][y][x] f32 -> xTp[b][66][66][256] bf16, styles folded --------
__global__ __launch_bounds__(512)
void xprep_kernel(const float* __restrict__ x, const float* __restrict__ s1,
                  ushort_t* __restrict__ xTp) {
    int tid = threadIdx.x;
    int b = blockIdx.y;
    int px_lin = blockIdx.x * 16 + (tid >> 5);
    int ic8 = tid & 31;
    int gy = px_lin >> 6, gx = px_lin & 63;
    const float* xb = x + (((size_t)b * C1) << 12) + (gy << 6) + gx;
    float4 slo = *(const float4*)(s1 + b * 256 + ic8 * 8);
    float4 shi = *(const float4*)(s1 + b * 256 + ic8 * 8 + 4);
    float sv[8] = {slo.x, slo.y, slo.z, slo.w, shi.x, shi.y, shi.z, shi.w};
    us8 h;
    #pragma unroll
    for (int j = 0; j < 8; j++) {
        float v = xb[((size_t)(ic8 * 8 + j)) << 12];
        h[j] = f2bf(v * sv[j]);
    }
    *(us8*)(xTp + (size_t)b * 66 * 66 * 256 + ((size_t)(gy + 1) * 66 + gx + 1) * 256 + ic8 * 8) = h;
}

// -------- upsample: y1T[b][64][64][256] -> y1up[b][130][130][256], *s2 folded --------
__global__ __launch_bounds__(256)
void upsample_kernel(const ushort_t* __restrict__ y1T, const float* __restrict__ s2,
                     ushort_t* __restrict__ y1up) {
    int flat = blockIdx.x * 256 + threadIdx.x;
    int b = blockIdx.y;
    int ic8 = flat & 31;
    int pxl = flat >> 5;
    int ux = pxl & 127, uy = pxl >> 7;
    int jyA; float wyA;
    if (uy & 1) { jyA = uy >> 1;       wyA = 0.75f; }
    else        { jyA = (uy >> 1) - 1; wyA = 0.25f; }
    int jxA; float wxA;
    if (ux & 1) { jxA = ux >> 1;       wxA = 0.75f; }
    else        { jxA = (ux >> 1) - 1; wxA = 0.25f; }
    int yA = clampi(jyA, 0, 63), yB = clampi(jyA + 1, 0, 63);
    int xA = clampi(jxA, 0, 63), xB = clampi(jxA + 1, 0, 63);
    float wyB = 1.f - wyA, wxB = 1.f - wxA;
    const ushort_t* yb = y1T + (size_t)b * 64 * 64 * 256 + ic8 * 8;
    us8 qAA = *(const us8*)(yb + (size_t)(yA * 64 + xA) * 256);
    us8 qAB = *(const us8*)(yb + (size_t)(yA * 64 + xB) * 256);
    us8 qBA = *(const us8*)(yb + (size_t)(yB * 64 + xA) * 256);
    us8 qBB = *(const us8*)(yb + (size_t)(yB * 64 + xB) * 256);
    float4 slo = *(const float4*)(s2 + b * 256 + ic8 * 8);
    float4 shi = *(const float4*)(s2 + b * 256 + ic8 * 8 + 4);
    float sv[8] = {slo.x, slo.y, slo.z, slo.w, shi.x, shi.y, shi.z, shi.w};
    us8 h;
    #pragma unroll
    for (int j = 0; j < 8; j++) {
        float v = wyA * (wxA * bf2f(qAA[j]) + wxB * bf2f(qAB[j]))
                + wyB * (wxA * bf2f(qBA[j]) + wxB * bf2f(qBB[j]));
        h[j] = f2bf(v * sv[j]);
    }
    *(us8*)(y1up + (size_t)b * 130 * 130 * 256 + ((size_t)(uy + 1) * 130 + ux + 1) * 256 + ic8 * 8) = h;
}

// =========== unified conv MFMA: 64 oc x (16x16 px) per block, all-LDS inner loop ===========
template<int ROWSTR, int OCTOT, int OUTW, int TPR, bool IS_CONV2>
__global__ __launch_bounds__(256, 2)
void conv_mfma(const ushort_t* __restrict__ inp, const ushort_t* __restrict__ wT,
               const float* __restrict__ dmod, const float* __restrict__ nza,
               ushort_t* __restrict__ outT,
               const float* __restrict__ rgb_in, const float* __restrict__ rw,
               const float* __restrict__ rb, float* __restrict__ xout,
               float* __restrict__ rgbo) {
    __shared__ __align__(16) ushort_t actS[18 * 18 * 32];   // 20736 B
    __shared__ __align__(16) ushort_t wS[9 * 64 * 32];      // 36864 B
    int b = blockIdx.z, ocg = blockIdx.y, tile = blockIdx.x;
    int tyT = tile / TPR, txT = tile % TPR;
    int ty0 = tyT * 16, tx0 = txT * 16;
    int tid = threadIdx.x, lane = tid & 63, wave = tid >> 6;
    int col = lane & 15, quad = lane >> 4;

    const ushort_t* inb = inp + (size_t)b * ROWSTR * ROWSTR * 256;

    int actOff[6]; bool actOk[6];
    #pragma unroll
    for (int i = 0; i < 6; i++) {
        int u = tid + 256 * i;
        actOk[i] = (u < 1296);
        int pxl = u >> 2, ic8 = u & 3;
        int py = pxl / 18, px = pxl - py * 18;
        actOff[i] = ((ty0 + py) * ROWSTR + tx0 + px) * 256 + ic8 * 8;
    }
    int wOff[9];
    #pragma unroll
    for (int i = 0; i < 9; i++) {
        int u = tid + 256 * i;
        int tap = u >> 8, oc = (u >> 2) & 63, ic8 = u & 3;
        wOff[i] = (tap * OCTOT + ocg * 64 + oc) * 256 + ic8 * 8;
    }

    us8 aReg[6], wReg[9];
#define LOADK(KC) { \
    _Pragma("unroll") for (int i = 0; i < 6; i++) \
        if (actOk[i]) aReg[i] = *(const us8*)(inb + actOff[i] + (KC) * 32); \
    _Pragma("unroll") for (int i = 0; i < 9; i++) \
        wReg[i] = *(const us8*)(wT + wOff[i] + (KC) * 32); }
#define STOREK() { \
    _Pragma("unroll") for (int i = 0; i < 6; i++) \
        if (actOk[i]) *(us8*)(actS + (size_t)(tid + 256 * i) * 8) = aReg[i]; \
    _Pragma("unroll") for (int i = 0; i < 9; i++) \
        *(us8*)(wS + (size_t)(tid + 256 * i) * 8) = wReg[i]; }

    f32x4 acc[4][4];
    #pragma unroll
    for (int mt = 0; mt < 4; mt++)
        #pragma unroll
        for (int nt = 0; nt < 4; nt++) acc[mt][nt] = (f32x4)(0.f);

    LOADK(0);
    STOREK();
    __syncthreads();

    for (int kc = 0; kc < 8; kc++) {
        if (kc < 7) LOADK(kc + 1);
        #pragma unroll
        for (int tap = 0; tap < 9; tap++) {
            const int dy = tap / 3, dx = tap % 3;
            bf16x8 a[4], bb[4];
            #pragma unroll
            for (int mt = 0; mt < 4; mt++)
                a[mt] = *(const bf16x8*)(wS + ((tap * 64 + mt * 16 + col) * 32 + quad * 8));
            #pragma unroll
            for (int nt = 0; nt < 4; nt++)
                bb[nt] = *(const bf16x8*)(actS + (((4 * wave + nt + dy) * 18 + col + dx) * 32 + quad * 8));
            #pragma unroll
            for (int mt = 0; mt < 4; mt++)
                #pragma unroll
                for (int nt = 0; nt < 4; nt++)
                    acc[mt][nt] = __builtin_amdgcn_mfma_f32_16x16x32_bf16(a[mt], bb[nt], acc[mt][nt], 0, 0, 0);
        }
        __syncthreads();
        if (kc < 7) { STOREK(); }
        __syncthreads();
    }
#undef LOADK
#undef STOREK

    if (!IS_CONV2) {
        #pragma unroll
        for (int mt = 0; mt < 4; mt++) {
            int oc0 = ocg * 64 + mt * 16 + quad * 4;
            float4 dv = *(const float4*)(dmod + b * OCTOT + oc0);
            float4 nv = *(const float4*)(nza + b * OCTOT + oc0);
            float dva[4] = {dv.x, dv.y, dv.z, dv.w};
            float nva[4] = {nv.x, nv.y, nv.z, nv.w};
            #pragma unroll
            for (int nt = 0; nt < 4; nt++) {
                int gy = ty0 + 4 * wave + nt, gx = tx0 + col;
                us4 h;
                #pragma unroll
                for (int r = 0; r < 4; r++) {
                    float t = acc[mt][nt][r] * dva[r] + nva[r];
                    t = (t >= 0.f) ? t : 0.1f * t;
                    h[r] = f2bf(t);
                }
                *(us4*)(outT + ((size_t)b * OUTW * OUTW + gy * OUTW + gx) * 256 + oc0) = h;
            }
        }
    } else {
        float dva[4][4], nva[4][4], rwa[3][4][4];
        #pragma unroll
        for (int mt = 0; mt < 4; mt++) {
            int oc0 = ocg * 64 + mt * 16 + quad * 4;
            float4 dv = *(const float4*)(dmod + b * 128 + oc0);
            float4 nv = *(const float4*)(nza + b * 128 + oc0);
            dva[mt][0] = dv.x; dva[mt][1] = dv.y; dva[mt][2] = dv.z; dva[mt][3] = dv.w;
            nva[mt][0] = nv.x; nva[mt][1] = nv.y; nva[mt][2] = nv.z; nva[mt][3] = nv.w;
            #pragma unroll
            for (int c = 0; c < 3; c++) {
                float4 rv = *(const float4*)(rw + c * 128 + oc0);
                rwa[c][mt][0] = rv.x; rwa[c][mt][1] = rv.y; rwa[c][mt][2] = rv.z; rwa[c][mt][3] = rv.w;
            }
        }
        #pragma unroll
        for (int nt = 0; nt < 4; nt++) {
            int uy = ty0 + 4 * wave + nt, ux = tx0 + col;
            float pc0 = 0.f, pc1 = 0.f, pc2 = 0.f;
            #pragma unroll
            for (int mt = 0; mt < 4; mt++) {
                int oc0 = ocg * 64 + mt * 16 + quad * 4;
                #pragma unroll
                for (int r = 0; r < 4; r++) {
                    float t = acc[mt][nt][r] * dva[mt][r] + nva[mt][r];
                    t = (t >= 0.f) ? t : 0.1f * t;
                    xout[(((size_t)b * 128 + oc0 + r) << 14) + (uy << 7) + ux] = t;
                    pc0 += rwa[0][mt][r] * t;
                    pc1 += rwa[1][mt][r] * t;
                    pc2 += rwa[2][mt][r] * t;
                }
            }
            // FIX: residual+bias must be added exactly ONCE per pixel.
            // Each pixel is covered by 4 threads (quad 0..3) x 2 blocks (ocg 0,1);
            // previous version added it in all 4 quads of ocg==0 -> 4x residual.
            if (ocg == 0 && quad == 0) {
                int jyA; float wyA;
                if (uy & 1) { jyA = uy >> 1;       wyA = 0.75f; }
                else        { jyA = (uy >> 1) - 1; wyA = 0.25f; }
                int jxA; float wxA;
                if (ux & 1) { jxA = ux >> 1;       wxA = 0.75f; }
                else        { jxA = (ux >> 1) - 1; wxA = 0.25f; }
                int yA = clampi(jyA, 0, 63), yB = clampi(jyA + 1, 0, 63);
                int xA = clampi(jxA, 0, 63), xB = clampi(jxA + 1, 0, 63);
                float wyB = 1.f - wyA, wxB = 1.f - wxA;
                const float* rp3 = rgb_in + (((size_t)b * 3) << 12);
                float up[3];
                #pragma unroll
                for (int c = 0; c < 3; c++) {
                    const float* rc = rp3 + ((size_t)c << 12);
                    up[c] = wyA * (wxA * rc[(yA << 6) + xA] + wxB * rc[(yA << 6) + xB])
                          + wyB * (wxA * rc[(yB << 6) + xA] + wxB * rc[(yB << 6) + xB]);
                }
                pc0 += rb[0] + up[0];
                pc1 += rb[1] + up[1];
                pc2 += rb[2] + up[2];
            }
            const float S = 0.70710678118654752f;
            atomicAdd(rgbo + (((size_t)b * 3 + 0) << 14) + (uy << 7) + ux, pc0 * S);
            atomicAdd(rgbo + (((size_t)b * 3 + 1) << 14) + (uy << 7) + ux, pc1 * S);
            atomicAdd(rgbo + (((size_t)b * 3 + 2) << 14) + (uy << 7) + ux, pc2 * S);
        }
    }
}

extern "C" void kernel_launch(void* const* d_in, const int* in_sizes, int n_in,
                              void* d_out, int out_size, void* d_ws, size_t ws_size,
                              hipStream_t stream) {
    (void)in_sizes; (void)n_in; (void)out_size; (void)ws_size;
    const float* x     = (const float*)d_in[0];
    const float* w     = (const float*)d_in[1];
    const float* n     = (const float*)d_in[2];
    const float* rgb   = (const float*)d_in[3];
    const float* cw1   = (const float*)d_in[4];
    const float* A1w   = (const float*)d_in[5];
    const float* A1b   = (const float*)d_in[6];
    const float* B1w   = (const float*)d_in[7];
    const float* B1b   = (const float*)d_in[8];
    const float* cw2   = (const float*)d_in[9];
    const float* A2w   = (const float*)d_in[10];
    const float* A2b   = (const float*)d_in[11];
    const float* B2w   = (const float*)d_in[12];
    const float* B2b   = (const float*)d_in[13];
    const float* rgbw  = (const float*)d_in[14];
    const float* rgbb  = (const float*)d_in[15];

    char* ws = (char*)d_ws;
    float* s1 = (float*)(ws);
    float* s2 = (float*)(ws + 8192);
    float* d1 = (float*)(ws + 16384);
    float* d2 = (float*)(ws + 24576);
    float* n1 = (float*)(ws + 28672);
    float* n2 = (float*)(ws + 36864);
    ushort_t* wT1  = (ushort_t*)(ws + 40960);          // 1179648 B
    ushort_t* wT2  = (ushort_t*)(ws + 1220608);        // 589824 B
    ushort_t* xTp  = (ushort_t*)(ws + 1810432);        // 17842176 B
    ushort_t* y1up = (ushort_t*)(ws + 19652608);       // 69222400 B
    ushort_t* y1T  = (ushort_t*)(ws + 88875008);       // 16777216 B

    float* xout = (float*)d_out;
    float* rgbo = xout + (size_t)BN * C2 * 128 * 128;

    hipMemsetAsync(xTp, 0, 17842176 + 69222400, stream);
    hipMemsetAsync(rgbo, 0, (size_t)BN * 3 * 128 * 128 * 4, stream);

    affine_kernel<<<1792, 256, 0, stream>>>(w, n, A1w, A1b, B1w, B1b, A2w, A2b, B2w, B2b,
                                            s1, s2, n1, n2);
    demod_kernel<<<768, 256, 0, stream>>>(cw1, cw2, s1, s2, d1, d2);
    wprep_kernel<<<(9 * 256 * 256 + 9 * 128 * 256 + 255) / 256, 256, 0, stream>>>(cw1, cw2, wT1, wT2);
    xprep_kernel<<<dim3(256, BN), 512, 0, stream>>>(x, s1, xTp);
    conv_mfma<66, 256, 64, 4, false><<<dim3(16, 4, BN), 256, 0, stream>>>(
        xTp, wT1, d1, n1, y1T, nullptr, nullptr, nullptr, nullptr, nullptr);
    upsample_kernel<<<dim3(2048, BN), 256, 0, stream>>>(y1T, s2, y1up);
    conv_mfma<130, 128, 128, 8, true><<<dim3(64, 2, BN), 256, 0, stream>>>(
        y1up, wT2, d2, n2, nullptr, rgb, rgbw, rgbb, xout, rgbo);
}